// Round 1
// baseline (1201.514 us; speedup 1.0000x reference)
//
#include <hip/hip_runtime.h>
#include <stdint.h>
#include <stddef.h>

#define NN 100000
#define NE 1600000
#define DD 32
#define NCAND 1024
#define HSIZE 65536
#define SORTN 4096
#define SCAN_B 1024

// ---------------- JAX threefry2x32 (20 rounds) ----------------
__host__ __device__ inline void tf2x32(uint32_t k0, uint32_t k1, uint32_t x0, uint32_t x1,
                                       uint32_t& o0, uint32_t& o1) {
  uint32_t ks2 = k0 ^ k1 ^ 0x1BD11BDAu;
  uint32_t v0 = x0 + k0, v1 = x1 + k1;
#define TFR(r) { v0 += v1; v1 = (v1 << (r)) | (v1 >> (32 - (r))); v1 ^= v0; }
  TFR(13) TFR(15) TFR(26) TFR(6)   v0 += k1;  v1 += ks2 + 1u;
  TFR(17) TFR(29) TFR(16) TFR(24)  v0 += ks2; v1 += k0 + 2u;
  TFR(13) TFR(15) TFR(26) TFR(6)   v0 += k0;  v1 += k1 + 3u;
  TFR(17) TFR(29) TFR(16) TFR(24)  v0 += k1;  v1 += ks2 + 4u;
  TFR(13) TFR(15) TFR(26) TFR(6)   v0 += ks2; v1 += k0 + 5u;
#undef TFR
  o0 = v0; o1 = v1;
}

// partitionable-mode 32-bit random bits for flat index i (counter hi=0, lo=i)
__device__ __forceinline__ uint32_t jax_bits32(uint32_t k0, uint32_t k1, uint32_t i) {
  uint32_t o0, o1;
  tf2x32(k0, k1, 0u, i, o0, o1);
  return o0 ^ o1;
}

__device__ __forceinline__ float bits_to_uniform(uint32_t b) {
  return __fsub_rn(__uint_as_float((b >> 9) | 0x3f800000u), 1.0f);
}

// numpy-pairwise sum of 32 floats: r[j] = ((x[j]+x[j+8])+x[j+16])+x[j+24], tree over r
__device__ __forceinline__ float pairwise32(const float* x) {
  float r[8];
#pragma unroll
  for (int j = 0; j < 8; ++j) r[j] = x[j];
#pragma unroll
  for (int b = 8; b < 32; b += 8)
#pragma unroll
    for (int j = 0; j < 8; ++j) r[j] = __fadd_rn(r[j], x[b + j]);
  float a01 = __fadd_rn(r[0], r[1]), a23 = __fadd_rn(r[2], r[3]);
  float a45 = __fadd_rn(r[4], r[5]), a67 = __fadd_rn(r[6], r[7]);
  return __fadd_rn(__fadd_rn(a01, a23), __fadd_rn(a45, a67));
}

// ---------------- kernels ----------------

// levels (consecutive dropout-keep prefix length) + per-row degree counts
__global__ void k_level_count(const int* __restrict__ rows,
                              uint32_t k00, uint32_t k01, uint32_t k10, uint32_t k11,
                              uint32_t k20, uint32_t k21,
                              uint8_t* __restrict__ level, int* __restrict__ cnt) {
  int e = blockIdx.x * blockDim.x + threadIdx.x;
  if (e >= NE) return;
  float u0 = bits_to_uniform(jax_bits32(k00, k01, (uint32_t)e));
  float u1 = bits_to_uniform(jax_bits32(k10, k11, (uint32_t)e));
  float u2 = bits_to_uniform(jax_bits32(k20, k21, (uint32_t)e));
  float kp0 = floorf(__fadd_rn(u0, 0.5f));
  float kp1 = floorf(__fadd_rn(u1, 0.25f));
  float kp2 = floorf(__fadd_rn(u2, 0.125f));
  int lv = 0;
  if (kp0 != 0.0f) { lv = 1; if (kp1 != 0.0f) { lv = 2; if (kp2 != 0.0f) lv = 3; } }
  level[e] = (uint8_t)lv;
  atomicAdd(&cnt[rows[e]], 1);
}

__global__ void k_scan1(const int* __restrict__ cnt, int* __restrict__ rp,
                        int* __restrict__ bsum, int n) {
  __shared__ int s[SCAN_B];
  int gid = blockIdx.x * SCAN_B + threadIdx.x;
  int v = (gid < n) ? cnt[gid] : 0;
  s[threadIdx.x] = v;
  __syncthreads();
  for (int off = 1; off < SCAN_B; off <<= 1) {
    int t = (threadIdx.x >= off) ? s[threadIdx.x - off] : 0;
    __syncthreads();
    s[threadIdx.x] += t;
    __syncthreads();
  }
  if (gid < n) rp[gid] = s[threadIdx.x] - v;  // exclusive
  if (threadIdx.x == SCAN_B - 1) bsum[blockIdx.x] = s[threadIdx.x];
}

__global__ void k_scan2(int* __restrict__ bsum, int nb) {
  __shared__ int s[128];
  int t = threadIdx.x;
  int v = (t < nb) ? bsum[t] : 0;
  s[t] = v;
  __syncthreads();
  for (int off = 1; off < 128; off <<= 1) {
    int x = (t >= off) ? s[t - off] : 0;
    __syncthreads();
    s[t] += x;
    __syncthreads();
  }
  if (t < nb) bsum[t] = s[t] - v;  // exclusive
}

__global__ void k_scan3(int* __restrict__ rp, const int* __restrict__ bsum, int n) {
  int gid = blockIdx.x * SCAN_B + threadIdx.x;
  if (gid < n) rp[gid] += bsum[gid / SCAN_B];
  if (gid == 0) rp[n] = NE;
}

__global__ void k_fill(const int* __restrict__ rows, const int* __restrict__ rp,
                       int* __restrict__ fill, int* __restrict__ eids) {
  int e = blockIdx.x * blockDim.x + threadIdx.x;
  if (e >= NE) return;
  int r = rows[e];
  int pos = rp[r] + atomicAdd(&fill[r], 1);
  eids[pos] = e;
}

// per-row: stable order (insertion sort eids asc), order0/1/2 (e-order sums), num init
__global__ void k_rowprep(const int* __restrict__ rp, int* __restrict__ eids,
                          const uint8_t* __restrict__ level, const float* __restrict__ adj,
                          float* __restrict__ order0, float* __restrict__ order1,
                          float* __restrict__ order2, float* __restrict__ num_cur,
                          float* __restrict__ num_sum) {
  int r = blockIdx.x * blockDim.x + threadIdx.x;
  if (r >= NN) return;
  int s = rp[r], t = rp[r + 1];
  for (int i = s + 1; i < t; ++i) {
    int key = eids[i];
    int j = i - 1;
    while (j >= s && eids[j] > key) { eids[j + 1] = eids[j]; --j; }
    eids[j + 1] = key;
  }
  float o0 = 0.0f, o1 = 0.0f, o2 = 0.0f;
  for (int k = s; k < t; ++k) {
    int e = eids[k];
    float a = adj[e];
    int lv = level[e];
    float z = __fmul_rn(a, 0.0f);
    o0 = __fadd_rn(o0, a);
    o1 = __fadd_rn(o1, (lv >= 1) ? a : z);
    o2 = __fadd_rn(o2, (lv >= 2) ? a : z);
  }
  order0[r] = o0; order1[r] = o1; order2[r] = o2;
  num_cur[r] = o0; num_sum[r] = o0;
}

// fst_emb = spmm(adj, embeds) - embeds ; emb_sum init
__global__ void k_emb0(const int* __restrict__ rp, const int* __restrict__ eids,
                       const int* __restrict__ cols, const float* __restrict__ adj,
                       const float* __restrict__ embeds, float* __restrict__ emb_cur,
                       float* __restrict__ emb_sum) {
  int tid = blockIdx.x * blockDim.x + threadIdx.x;
  int r = tid >> 5, d = tid & 31;
  if (r >= NN) return;
  int s = rp[r], t = rp[r + 1];
  float acc = 0.0f;
  for (int k = s; k < t; ++k) {
    int e = eids[k];
    float x = embeds[cols[e] * DD + d];
    acc = __fadd_rn(acc, __fmul_rn(adj[e], x));
  }
  float fe = __fsub_rn(acc, embeds[r * DD + d]);
  emb_cur[r * DD + d] = fe;
  emb_sum[r * DD + d] = fe;
}

// emb_next = spmm(vals_stage, emb_cur) - emb_cur - order*emb_cur ; emb_sum += emb_next
__global__ void k_emb_step(const int* __restrict__ rp, const int* __restrict__ eids,
                           const int* __restrict__ cols, const float* __restrict__ adj,
                           const uint8_t* __restrict__ level, int stage,
                           const float* __restrict__ order, const float* __restrict__ emb_cur,
                           float* __restrict__ emb_next, float* __restrict__ emb_sum) {
  int tid = blockIdx.x * blockDim.x + threadIdx.x;
  int r = tid >> 5, d = tid & 31;
  if (r >= NN) return;
  int s = rp[r], t = rp[r + 1];
  float acc = 0.0f;
  for (int k = s; k < t; ++k) {
    int e = eids[k];
    float a = adj[e];
    float v = (level[e] >= stage) ? a : __fmul_rn(a, 0.0f);
    float x = emb_cur[cols[e] * DD + d];
    acc = __fadd_rn(acc, __fmul_rn(v, x));
  }
  float ec = emb_cur[r * DD + d];
  float o = __fsub_rn(acc, ec);
  o = __fsub_rn(o, __fmul_rn(order[r], ec));
  int idx = r * DD + d;
  emb_next[idx] = o;
  emb_sum[idx] = __fadd_rn(emb_sum[idx], o);
}

// num_next = spmm(vals_stage, num_cur) - num_cur - order ; num_sum += num_next
__global__ void k_num_step(const int* __restrict__ rp, const int* __restrict__ eids,
                           const int* __restrict__ cols, const float* __restrict__ adj,
                           const uint8_t* __restrict__ level, int stage,
                           const float* __restrict__ order, const float* __restrict__ num_cur,
                           float* __restrict__ num_next, float* __restrict__ num_sum) {
  int r = blockIdx.x * blockDim.x + threadIdx.x;
  if (r >= NN) return;
  int s = rp[r], t = rp[r + 1];
  float acc = 0.0f;
  for (int k = s; k < t; ++k) {
    int e = eids[k];
    float a = adj[e];
    float v = (level[e] >= stage) ? a : __fmul_rn(a, 0.0f);
    acc = __fadd_rn(acc, __fmul_rn(v, num_cur[cols[e]]));
  }
  float o = __fsub_rn(__fsub_rn(acc, num_cur[r]), order[r]);
  num_next[r] = o;
  num_sum[r] = __fadd_rn(num_sum[r], o);
}

__global__ void k_final(const float* __restrict__ embeds, const float* __restrict__ emb_sum,
                        const float* __restrict__ num_sum, uint32_t gk0, uint32_t gk1,
                        float* __restrict__ out_scores, int* __restrict__ hist) {
  int r = blockIdx.x * blockDim.x + threadIdx.x;
  if (r >= NN) return;
  float denom = __fadd_rn(num_sum[r], 1e-8f);
  float sub[DD], em[DD], pr[DD];
  const float4* ps = (const float4*)(emb_sum + (size_t)r * DD);
  const float4* pe = (const float4*)(embeds + (size_t)r * DD);
#pragma unroll
  for (int j = 0; j < 8; ++j) {
    float4 a = ps[j], b = pe[j];
    sub[4 * j + 0] = __fdiv_rn(a.x, denom); sub[4 * j + 1] = __fdiv_rn(a.y, denom);
    sub[4 * j + 2] = __fdiv_rn(a.z, denom); sub[4 * j + 3] = __fdiv_rn(a.w, denom);
    em[4 * j + 0] = b.x; em[4 * j + 1] = b.y; em[4 * j + 2] = b.z; em[4 * j + 3] = b.w;
  }
#pragma unroll
  for (int d = 0; d < DD; ++d) pr[d] = __fmul_rn(sub[d], sub[d]);
  float n1 = fmaxf(__fsqrt_rn(pairwise32(pr)), 1e-12f);
#pragma unroll
  for (int d = 0; d < DD; ++d) pr[d] = __fmul_rn(em[d], em[d]);
  float n2 = fmaxf(__fsqrt_rn(pairwise32(pr)), 1e-12f);
#pragma unroll
  for (int d = 0; d < DD; ++d)
    pr[d] = __fmul_rn(__fdiv_rn(sub[d], n1), __fdiv_rn(em[d], n2));
  float dot = pairwise32(pr);
  // Gumbel: -log(-log(u)), log via double (correctly-rounded f32 proxy)
  float u = bits_to_uniform(jax_bits32(gk0, gk1, (uint32_t)r));
  float l1 = (float)log((double)u);
  float w = -l1;
  float l2 = (float)log((double)w);
  float g = -l2;
  float score = __fadd_rn(dot, g);
  out_scores[r] = score;
  uint32_t kb = __float_as_uint(score);
  kb = (kb & 0x80000000u) ? ~kb : (kb | 0x80000000u);
  atomicAdd(&hist[kb >> 16], 1);
}

__global__ void k_cutoff(const int* __restrict__ hist, int* __restrict__ cutoff) {
  __shared__ int psum[1024];
  int t = threadIdx.x;
  int base = HSIZE - (t + 1) * 64;  // descending chunks of 64 bins
  int own = 0;
  for (int i = 0; i < 64; ++i) own += hist[base + i];
  psum[t] = own;
  __syncthreads();
  for (int off = 1; off < 1024; off <<= 1) {
    int v = (t >= off) ? psum[t - off] : 0;
    __syncthreads();
    psum[t] += v;
    __syncthreads();
  }
  int incl = psum[t];
  int prev = incl - own;
  if (incl >= NCAND && prev < NCAND) {
    int c = prev;
    int b = HSIZE - t * 64 - 1;
    while (b >= base) {
      c += hist[b];
      if (c >= NCAND) break;
      --b;
    }
    *cutoff = b;
  }
}

__global__ void k_collect(const float* __restrict__ scores, const int* __restrict__ cutoff,
                          unsigned long long* __restrict__ buf, int* __restrict__ cnt2) {
  int r = blockIdx.x * blockDim.x + threadIdx.x;
  if (r >= NN) return;
  uint32_t kb = __float_as_uint(scores[r]);
  kb = (kb & 0x80000000u) ? ~kb : (kb | 0x80000000u);
  if ((int)(kb >> 16) >= *cutoff) {
    int p = atomicAdd(cnt2, 1);
    if (p < SORTN)
      buf[p] = ((unsigned long long)kb << 32) | (uint32_t)(~(uint32_t)r);
  }
}

__global__ __launch_bounds__(1024) void k_sort(const unsigned long long* __restrict__ buf,
                                               const int* __restrict__ cnt2,
                                               float* __restrict__ out_cand) {
  __shared__ unsigned long long s[SORTN];
  int m = *cnt2;
  if (m > SORTN) m = SORTN;
  for (int i = threadIdx.x; i < SORTN; i += 1024) s[i] = (i < m) ? buf[i] : 0ull;
  __syncthreads();
  for (int k = 2; k <= SORTN; k <<= 1) {
    for (int j = k >> 1; j > 0; j >>= 1) {
      for (int i = threadIdx.x; i < SORTN; i += 1024) {
        int ixj = i ^ j;
        if (ixj > i) {
          unsigned long long a = s[i], b = s[ixj];
          bool desc = ((i & k) == 0);
          if (desc ? (a < b) : (a > b)) { s[i] = b; s[ixj] = a; }
        }
      }
      __syncthreads();
    }
  }
  for (int i = threadIdx.x; i < NCAND; i += 1024) {
    uint32_t idx = ~((uint32_t)(s[i] & 0xffffffffull));
    out_cand[i] = (float)idx;
  }
}

// ---------------- host ----------------
extern "C" void kernel_launch(void* const* d_in, const int* in_sizes, int n_in,
                              void* d_out, int out_size, void* d_ws, size_t ws_size,
                              hipStream_t stream) {
  const int* rows = (const int*)d_in[0];
  const int* cols = rows + NE;
  const float* adj = (const float*)d_in[1];
  const float* embeds = (const float*)d_in[2];
  float* out = (float*)d_out;

  char* p = (char*)d_ws;
  auto alloc = [&](size_t bytes) {
    char* q = p;
    p += (bytes + 255) & ~(size_t)255;
    return q;
  };
  int* rp = (int*)alloc((NN + 1) * 4);
  int* cnt = (int*)alloc(NN * 4);
  int* eids = (int*)alloc((size_t)NE * 4);
  uint8_t* level = (uint8_t*)alloc(NE);
  float* order0 = (float*)alloc(NN * 4);
  float* order1 = (float*)alloc(NN * 4);
  float* order2 = (float*)alloc(NN * 4);
  float* embA = (float*)alloc((size_t)NN * DD * 4);
  float* embB = (float*)alloc((size_t)NN * DD * 4);
  float* embS = (float*)alloc((size_t)NN * DD * 4);
  float* numA = (float*)alloc(NN * 4);
  float* numB = (float*)alloc(NN * 4);
  float* numS = (float*)alloc(NN * 4);
  int* hist = (int*)alloc(HSIZE * 4);
  int* bsum = (int*)alloc(4096);
  unsigned long long* buf = (unsigned long long*)alloc(SORTN * 8);
  int* cnt2 = (int*)alloc(256);  // [0]=collect count, [1]=cutoff bin

  // folded dropout keys: fold_in(key(42), i) = threefry((0,42),(0,i))
  uint32_t dk[3][2];
  for (int i = 0; i < 3; ++i) tf2x32(0u, 42u, 0u, (uint32_t)i, dk[i][0], dk[i][1]);

  hipMemsetAsync(cnt, 0, NN * 4, stream);
  hipMemsetAsync(hist, 0, HSIZE * 4, stream);
  hipMemsetAsync(cnt2, 0, 8, stream);

  k_level_count<<<(NE + 255) / 256, 256, 0, stream>>>(
      rows, dk[0][0], dk[0][1], dk[1][0], dk[1][1], dk[2][0], dk[2][1], level, cnt);

  int nb = (NN + SCAN_B - 1) / SCAN_B;  // 98
  k_scan1<<<nb, SCAN_B, 0, stream>>>(cnt, rp, bsum, NN);
  k_scan2<<<1, 128, 0, stream>>>(bsum, nb);
  k_scan3<<<nb, SCAN_B, 0, stream>>>(rp, bsum, NN);

  hipMemsetAsync(cnt, 0, NN * 4, stream);
  k_fill<<<(NE + 255) / 256, 256, 0, stream>>>(rows, rp, cnt, eids);
  k_rowprep<<<(NN + 255) / 256, 256, 0, stream>>>(rp, eids, level, adj, order0, order1,
                                                  order2, numA, numS);
  k_emb0<<<(NN * DD + 255) / 256, 256, 0, stream>>>(rp, eids, cols, adj, embeds, embA, embS);

  float* ec = embA; float* en = embB;
  float* nc = numA; float* nx = numB;
  const float* ords[3] = {order0, order1, order2};
  for (int i = 0; i < 3; ++i) {
    k_emb_step<<<(NN * DD + 255) / 256, 256, 0, stream>>>(rp, eids, cols, adj, level, i + 1,
                                                          ords[i], ec, en, embS);
    k_num_step<<<(NN + 255) / 256, 256, 0, stream>>>(rp, eids, cols, adj, level, i + 1,
                                                     ords[i], nc, nx, numS);
    float* t = ec; ec = en; en = t;
    t = nc; nc = nx; nx = t;
  }

  k_final<<<(NN + 255) / 256, 256, 0, stream>>>(embeds, embS, numS, 0u, 7u, out, hist);
  k_cutoff<<<1, 1024, 0, stream>>>(hist, cnt2 + 1);
  k_collect<<<(NN + 255) / 256, 256, 0, stream>>>(out, cnt2 + 1, buf, cnt2);
  k_sort<<<1, 1024, 0, stream>>>(buf, cnt2, out + NN);
}

// Round 2
// 689.454 us; speedup vs baseline: 1.7427x; 1.7427x over previous
//
#include <hip/hip_runtime.h>
#include <stdint.h>
#include <stddef.h>

#define NN 100000
#define NE 1600000
#define DD 32
#define NCAND 1024
#define HSIZE 65536
#define SORTN 4096
#define SCAN_B 1024
#define NB ((NN + SCAN_B - 1) / SCAN_B)   // 98 blocks per scan array

// capacity for per-stage packed lists (mean + huge margin)
#define CAP1 832000
#define CAP2 432000
#define CAP3 240000

// ---------------- JAX threefry2x32 (20 rounds) ----------------
__host__ __device__ inline void tf2x32(uint32_t k0, uint32_t k1, uint32_t x0, uint32_t x1,
                                       uint32_t& o0, uint32_t& o1) {
  uint32_t ks2 = k0 ^ k1 ^ 0x1BD11BDAu;
  uint32_t v0 = x0 + k0, v1 = x1 + k1;
#define TFR(r) { v0 += v1; v1 = (v1 << (r)) | (v1 >> (32 - (r))); v1 ^= v0; }
  TFR(13) TFR(15) TFR(26) TFR(6)   v0 += k1;  v1 += ks2 + 1u;
  TFR(17) TFR(29) TFR(16) TFR(24)  v0 += ks2; v1 += k0 + 2u;
  TFR(13) TFR(15) TFR(26) TFR(6)   v0 += k0;  v1 += k1 + 3u;
  TFR(17) TFR(29) TFR(16) TFR(24)  v0 += k1;  v1 += ks2 + 4u;
  TFR(13) TFR(15) TFR(26) TFR(6)   v0 += ks2; v1 += k0 + 5u;
#undef TFR
  o0 = v0; o1 = v1;
}

__device__ __forceinline__ uint32_t jax_bits32(uint32_t k0, uint32_t k1, uint32_t i) {
  uint32_t o0, o1;
  tf2x32(k0, k1, 0u, i, o0, o1);
  return o0 ^ o1;
}

__device__ __forceinline__ float bits_to_uniform(uint32_t b) {
  return __fsub_rn(__uint_as_float((b >> 9) | 0x3f800000u), 1.0f);
}

// numpy-pairwise sum of 32 floats
__device__ __forceinline__ float pairwise32(const float* x) {
  float r[8];
#pragma unroll
  for (int j = 0; j < 8; ++j) r[j] = x[j];
#pragma unroll
  for (int b = 8; b < 32; b += 8)
#pragma unroll
    for (int j = 0; j < 8; ++j) r[j] = __fadd_rn(r[j], x[b + j]);
  float a01 = __fadd_rn(r[0], r[1]), a23 = __fadd_rn(r[2], r[3]);
  float a45 = __fadd_rn(r[4], r[5]), a67 = __fadd_rn(r[6], r[7]);
  return __fadd_rn(__fadd_rn(a01, a23), __fadd_rn(a45, a67));
}

// ---------------- kernels ----------------

// levels + per-row per-stage degree counts (cntAll = 4 arrays of NN)
__global__ void k_level_count(const int* __restrict__ rows,
                              uint32_t k00, uint32_t k01, uint32_t k10, uint32_t k11,
                              uint32_t k20, uint32_t k21,
                              uint8_t* __restrict__ level, int* __restrict__ cntAll) {
  int e = blockIdx.x * blockDim.x + threadIdx.x;
  if (e >= NE) return;
  float u0 = bits_to_uniform(jax_bits32(k00, k01, (uint32_t)e));
  float u1 = bits_to_uniform(jax_bits32(k10, k11, (uint32_t)e));
  float u2 = bits_to_uniform(jax_bits32(k20, k21, (uint32_t)e));
  float kp0 = floorf(__fadd_rn(u0, 0.5f));
  float kp1 = floorf(__fadd_rn(u1, 0.25f));
  float kp2 = floorf(__fadd_rn(u2, 0.125f));
  int lv = 0;
  if (kp0 != 0.0f) { lv = 1; if (kp1 != 0.0f) { lv = 2; if (kp2 != 0.0f) lv = 3; } }
  level[e] = (uint8_t)lv;
  int r = rows[e];
  atomicAdd(&cntAll[r], 1);
  if (lv >= 1) atomicAdd(&cntAll[NN + r], 1);
  if (lv >= 2) atomicAdd(&cntAll[2 * NN + r], 1);
  if (lv >= 3) atomicAdd(&cntAll[3 * NN + r], 1);
}

// multi-array exclusive scan: grid (NB, 4)
__global__ void k_scan1(const int* __restrict__ cntAll, int* __restrict__ rpAll,
                        int* __restrict__ bsumAll) {
  __shared__ int s[SCAN_B];
  int a = blockIdx.y;
  const int* cnt = cntAll + (size_t)a * NN;
  int* rp = rpAll + (size_t)a * (NN + 1);
  int gid = blockIdx.x * SCAN_B + threadIdx.x;
  int v = (gid < NN) ? cnt[gid] : 0;
  s[threadIdx.x] = v;
  __syncthreads();
  for (int off = 1; off < SCAN_B; off <<= 1) {
    int t = (threadIdx.x >= off) ? s[threadIdx.x - off] : 0;
    __syncthreads();
    s[threadIdx.x] += t;
    __syncthreads();
  }
  if (gid < NN) rp[gid] = s[threadIdx.x] - v;  // exclusive
  if (threadIdx.x == SCAN_B - 1) bsumAll[a * 128 + blockIdx.x] = s[threadIdx.x];
}

__global__ void k_scan2(int* __restrict__ bsumAll) {
  __shared__ int s[128];
  int* bsum = bsumAll + blockIdx.x * 128;
  int t = threadIdx.x;
  int v = (t < NB) ? bsum[t] : 0;
  s[t] = v;
  __syncthreads();
  for (int off = 1; off < 128; off <<= 1) {
    int x = (t >= off) ? s[t - off] : 0;
    __syncthreads();
    s[t] += x;
    __syncthreads();
  }
  if (t < NB) bsum[t] = s[t] - v;  // exclusive
}

__global__ void k_scan3(int* __restrict__ rpAll, const int* __restrict__ bsumAll,
                        const int* __restrict__ cntAll) {
  int a = blockIdx.y;
  int* rp = rpAll + (size_t)a * (NN + 1);
  int gid = blockIdx.x * SCAN_B + threadIdx.x;
  if (gid < NN) {
    int v = rp[gid] + bsumAll[a * 128 + blockIdx.x];
    rp[gid] = v;
    if (gid == NN - 1) rp[NN] = v + cntAll[(size_t)a * NN + gid];
  }
}

__global__ void k_fill(const int* __restrict__ rows, const int* __restrict__ rp0,
                       int* __restrict__ cursor, int* __restrict__ eids) {
  int e = blockIdx.x * blockDim.x + threadIdx.x;
  if (e >= NE) return;
  int r = rows[e];
  int pos = rp0[r] + atomicAdd(&cursor[r], 1);
  eids[pos] = e;
}

// per-row: stable sort eids asc, emit packed per-stage lists, order sums
__global__ void k_build(const int* __restrict__ rpAll, int* __restrict__ eids,
                        const int* __restrict__ cols, const float* __restrict__ adj,
                        const uint8_t* __restrict__ level,
                        int2* __restrict__ pk0, int2* __restrict__ pk1,
                        int2* __restrict__ pk2, int2* __restrict__ pk3,
                        float* __restrict__ order0, float* __restrict__ order1,
                        float* __restrict__ order2) {
  int r = blockIdx.x * blockDim.x + threadIdx.x;
  if (r >= NN) return;
  const int* rp0 = rpAll;
  const int* rp1 = rpAll + (NN + 1);
  const int* rp2 = rpAll + 2 * (NN + 1);
  const int* rp3 = rpAll + 3 * (NN + 1);
  int s = rp0[r], t = rp0[r + 1];
  int d = t - s;
  int loc[96];
  int* src;
  if (d <= 96) {
    for (int i = 0; i < d; ++i) loc[i] = eids[s + i];
    for (int i = 1; i < d; ++i) {
      int key = loc[i];
      int j = i - 1;
      while (j >= 0 && loc[j] > key) { loc[j + 1] = loc[j]; --j; }
      loc[j + 1] = key;
    }
    src = loc;
  } else {
    // effectively-never fallback: in-place global insertion sort
    for (int i = s + 1; i < t; ++i) {
      int key = eids[i];
      int j = i - 1;
      while (j >= s && eids[j] > key) { eids[j + 1] = eids[j]; --j; }
      eids[j + 1] = key;
    }
    src = eids + s;
  }
  float o0 = 0.0f, o1 = 0.0f, o2 = 0.0f;
  int p0 = s, p1 = rp1[r], p2 = rp2[r], p3 = rp3[r];
  for (int i = 0; i < d; ++i) {
    int e = src[i];
    int c = cols[e];
    float a = adj[e];
    int lv = level[e];
    int2 pk = make_int2(c, __float_as_int(a));
    o0 = __fadd_rn(o0, a);
    pk0[p0++] = pk;
    if (lv >= 1) {
      o1 = __fadd_rn(o1, a);
      pk1[p1++] = pk;
      if (lv >= 2) {
        o2 = __fadd_rn(o2, a);
        pk2[p2++] = pk;
        if (lv >= 3) pk3[p3++] = pk;
      }
    }
  }
  order0[r] = o0; order1[r] = o1; order2[r] = o2;
}

// fst_emb = spmm(adj, embeds) - embeds  (write E0 only)
__global__ void k_emb0(const int* __restrict__ rp, const int2* __restrict__ pk,
                       const float* __restrict__ embeds, float* __restrict__ e0) {
  int tid = blockIdx.x * blockDim.x + threadIdx.x;
  int r = tid >> 5, d = tid & 31;
  if (r >= NN) return;
  int s = rp[r], t = rp[r + 1];
  float acc = 0.0f;
  for (int base = s; base < t; base += 32) {
    int idx = base + d;
    int2 p = (idx < t) ? pk[idx] : make_int2(0, 0);
    int m = t - base; if (m > 32) m = 32;
    for (int j = 0; j < m; ++j) {
      int c = __shfl(p.x, j, 32);
      int ab = __shfl(p.y, j, 32);
      float x = embeds[(size_t)c * DD + d];
      acc = __fadd_rn(acc, __fmul_rn(__int_as_float(ab), x));
    }
  }
  e0[(size_t)r * DD + d] = __fsub_rn(acc, embeds[(size_t)r * DD + d]);
}

// emb_next = spmm(stage vals, emb_cur) - emb_cur - order*emb_cur
// mode: 1 = S = ec + o (init), write next; 2 = S += o, write next; 3 = S += o only
__global__ void k_emb_step(const int* __restrict__ rp, const int2* __restrict__ pk,
                           const float* __restrict__ ord, const float* __restrict__ ecur,
                           float* __restrict__ enext, float* __restrict__ esum, int mode) {
  int tid = blockIdx.x * blockDim.x + threadIdx.x;
  int r = tid >> 5, d = tid & 31;
  if (r >= NN) return;
  int s = rp[r], t = rp[r + 1];
  float acc = 0.0f;
  for (int base = s; base < t; base += 32) {
    int idx = base + d;
    int2 p = (idx < t) ? pk[idx] : make_int2(0, 0);
    int m = t - base; if (m > 32) m = 32;
    for (int j = 0; j < m; ++j) {
      int c = __shfl(p.x, j, 32);
      int ab = __shfl(p.y, j, 32);
      float x = ecur[(size_t)c * DD + d];
      acc = __fadd_rn(acc, __fmul_rn(__int_as_float(ab), x));
    }
  }
  size_t idx = (size_t)r * DD + d;
  float ec = ecur[idx];
  float o = __fsub_rn(__fsub_rn(acc, ec), __fmul_rn(ord[r], ec));
  if (mode != 3) enext[idx] = o;
  if (mode == 1) esum[idx] = __fadd_rn(ec, o);
  else esum[idx] = __fadd_rn(esum[idx], o);
}

// num_next = spmm(stage vals, num_cur) - num_cur - order
__global__ void k_num_step(const int* __restrict__ rp, const int2* __restrict__ pk,
                           const float* __restrict__ ord, const float* __restrict__ ncur,
                           float* __restrict__ nnext, float* __restrict__ nsum, int mode) {
  int r = blockIdx.x * blockDim.x + threadIdx.x;
  if (r >= NN) return;
  int s = rp[r], t = rp[r + 1];
  float acc = 0.0f;
  for (int k = s; k < t; ++k) {
    int2 p = pk[k];
    acc = __fadd_rn(acc, __fmul_rn(__int_as_float(p.y), ncur[p.x]));
  }
  float nc = ncur[r];
  float o = __fsub_rn(__fsub_rn(acc, nc), ord[r]);
  if (mode != 3) nnext[r] = o;
  if (mode == 1) nsum[r] = __fadd_rn(nc, o);
  else nsum[r] = __fadd_rn(nsum[r], o);
}

__global__ void k_final(const float* __restrict__ embeds, const float* __restrict__ emb_sum,
                        const float* __restrict__ num_sum, uint32_t gk0, uint32_t gk1,
                        float* __restrict__ out_scores, int* __restrict__ hist) {
  int r = blockIdx.x * blockDim.x + threadIdx.x;
  if (r >= NN) return;
  float denom = __fadd_rn(num_sum[r], 1e-8f);
  float sub[DD], em[DD], pr[DD];
  const float4* ps = (const float4*)(emb_sum + (size_t)r * DD);
  const float4* pe = (const float4*)(embeds + (size_t)r * DD);
#pragma unroll
  for (int j = 0; j < 8; ++j) {
    float4 a = ps[j], b = pe[j];
    sub[4 * j + 0] = __fdiv_rn(a.x, denom); sub[4 * j + 1] = __fdiv_rn(a.y, denom);
    sub[4 * j + 2] = __fdiv_rn(a.z, denom); sub[4 * j + 3] = __fdiv_rn(a.w, denom);
    em[4 * j + 0] = b.x; em[4 * j + 1] = b.y; em[4 * j + 2] = b.z; em[4 * j + 3] = b.w;
  }
#pragma unroll
  for (int d = 0; d < DD; ++d) pr[d] = __fmul_rn(sub[d], sub[d]);
  float n1 = fmaxf(__fsqrt_rn(pairwise32(pr)), 1e-12f);
#pragma unroll
  for (int d = 0; d < DD; ++d) pr[d] = __fmul_rn(em[d], em[d]);
  float n2 = fmaxf(__fsqrt_rn(pairwise32(pr)), 1e-12f);
#pragma unroll
  for (int d = 0; d < DD; ++d)
    pr[d] = __fmul_rn(__fdiv_rn(sub[d], n1), __fdiv_rn(em[d], n2));
  float dot = pairwise32(pr);
  float u = bits_to_uniform(jax_bits32(gk0, gk1, (uint32_t)r));
  float l1 = (float)log((double)u);
  float w = -l1;
  float l2 = (float)log((double)w);
  float g = -l2;
  float score = __fadd_rn(dot, g);
  out_scores[r] = score;
  uint32_t kb = __float_as_uint(score);
  kb = (kb & 0x80000000u) ? ~kb : (kb | 0x80000000u);
  atomicAdd(&hist[kb >> 16], 1);
}

__global__ void k_cutoff(const int* __restrict__ hist, int* __restrict__ cutoff) {
  __shared__ int psum[1024];
  int t = threadIdx.x;
  int base = HSIZE - (t + 1) * 64;
  int own = 0;
  for (int i = 0; i < 64; ++i) own += hist[base + i];
  psum[t] = own;
  __syncthreads();
  for (int off = 1; off < 1024; off <<= 1) {
    int v = (t >= off) ? psum[t - off] : 0;
    __syncthreads();
    psum[t] += v;
    __syncthreads();
  }
  int incl = psum[t];
  int prev = incl - own;
  if (incl >= NCAND && prev < NCAND) {
    int c = prev;
    int b = HSIZE - t * 64 - 1;
    while (b >= base) {
      c += hist[b];
      if (c >= NCAND) break;
      --b;
    }
    *cutoff = b;
  }
}

__global__ void k_collect(const float* __restrict__ scores, const int* __restrict__ cutoff,
                          unsigned long long* __restrict__ buf, int* __restrict__ cnt2) {
  int r = blockIdx.x * blockDim.x + threadIdx.x;
  if (r >= NN) return;
  uint32_t kb = __float_as_uint(scores[r]);
  kb = (kb & 0x80000000u) ? ~kb : (kb | 0x80000000u);
  if ((int)(kb >> 16) >= *cutoff) {
    int p = atomicAdd(cnt2, 1);
    if (p < SORTN)
      buf[p] = ((unsigned long long)kb << 32) | (uint32_t)(~(uint32_t)r);
  }
}

__global__ __launch_bounds__(1024) void k_sort(const unsigned long long* __restrict__ buf,
                                               const int* __restrict__ cnt2,
                                               float* __restrict__ out_cand) {
  __shared__ unsigned long long s[SORTN];
  int m = *cnt2;
  if (m > SORTN) m = SORTN;
  for (int i = threadIdx.x; i < SORTN; i += 1024) s[i] = (i < m) ? buf[i] : 0ull;
  __syncthreads();
  for (int k = 2; k <= SORTN; k <<= 1) {
    for (int j = k >> 1; j > 0; j >>= 1) {
      for (int i = threadIdx.x; i < SORTN; i += 1024) {
        int ixj = i ^ j;
        if (ixj > i) {
          unsigned long long a = s[i], b = s[ixj];
          bool desc = ((i & k) == 0);
          if (desc ? (a < b) : (a > b)) { s[i] = b; s[ixj] = a; }
        }
      }
      __syncthreads();
    }
  }
  for (int i = threadIdx.x; i < NCAND; i += 1024) {
    uint32_t idx = ~((uint32_t)(s[i] & 0xffffffffull));
    out_cand[i] = (float)idx;
  }
}

// ---------------- host ----------------
extern "C" void kernel_launch(void* const* d_in, const int* in_sizes, int n_in,
                              void* d_out, int out_size, void* d_ws, size_t ws_size,
                              hipStream_t stream) {
  const int* rows = (const int*)d_in[0];
  const int* cols = rows + NE;
  const float* adj = (const float*)d_in[1];
  const float* embeds = (const float*)d_in[2];
  float* out = (float*)d_out;

  char* p = (char*)d_ws;
  auto alloc = [&](size_t bytes) {
    char* q = p;
    p += (bytes + 255) & ~(size_t)255;
    return q;
  };
  // single contiguous zero region: cntAll(4*NN) | cursor(NN) | hist | cnt2
  size_t zero_bytes = (size_t)(4 * NN + NN + HSIZE) * 4 + 256;
  char* zero_base = (char*)alloc(zero_bytes);
  int* cntAll = (int*)zero_base;
  int* cursor = cntAll + 4 * NN;
  int* hist = cursor + NN;
  int* cnt2 = hist + HSIZE;  // [0]=collect count, [1]=cutoff bin

  int* rpAll = (int*)alloc((size_t)4 * (NN + 1) * 4);
  int* bsumAll = (int*)alloc(4 * 128 * 4);
  int* eids = (int*)alloc((size_t)NE * 4);
  uint8_t* level = (uint8_t*)alloc(NE);
  int2* pk0 = (int2*)alloc((size_t)NE * 8);
  int2* pk1 = (int2*)alloc((size_t)CAP1 * 8);
  int2* pk2 = (int2*)alloc((size_t)CAP2 * 8);
  int2* pk3 = (int2*)alloc((size_t)CAP3 * 8);
  float* order0 = (float*)alloc(NN * 4);
  float* order1 = (float*)alloc(NN * 4);
  float* order2 = (float*)alloc(NN * 4);
  float* embA = (float*)alloc((size_t)NN * DD * 4);
  float* embB = (float*)alloc((size_t)NN * DD * 4);
  float* embS = (float*)alloc((size_t)NN * DD * 4);
  float* num1 = (float*)alloc(NN * 4);
  float* num2 = (float*)alloc(NN * 4);
  float* numS = (float*)alloc(NN * 4);
  unsigned long long* buf = (unsigned long long*)alloc(SORTN * 8);

  uint32_t dk[3][2];
  for (int i = 0; i < 3; ++i) tf2x32(0u, 42u, 0u, (uint32_t)i, dk[i][0], dk[i][1]);

  hipMemsetAsync(zero_base, 0, zero_bytes, stream);

  k_level_count<<<(NE + 255) / 256, 256, 0, stream>>>(
      rows, dk[0][0], dk[0][1], dk[1][0], dk[1][1], dk[2][0], dk[2][1], level, cntAll);

  dim3 sg(NB, 4);
  k_scan1<<<sg, SCAN_B, 0, stream>>>(cntAll, rpAll, bsumAll);
  k_scan2<<<4, 128, 0, stream>>>(bsumAll);
  k_scan3<<<sg, SCAN_B, 0, stream>>>(rpAll, bsumAll, cntAll);

  k_fill<<<(NE + 255) / 256, 256, 0, stream>>>(rows, rpAll, cursor, eids);
  k_build<<<(NN + 255) / 256, 256, 0, stream>>>(rpAll, eids, cols, adj, level, pk0, pk1,
                                                pk2, pk3, order0, order1, order2);

  const int* rp0 = rpAll;
  const int* rp1 = rpAll + (NN + 1);
  const int* rp2 = rpAll + 2 * (NN + 1);
  const int* rp3 = rpAll + 3 * (NN + 1);

  int gEmb = (NN * 32 + 255) / 256;
  k_emb0<<<gEmb, 256, 0, stream>>>(rp0, pk0, embeds, embA);

  // stage 1: cur=embA -> next=embB, S init
  k_emb_step<<<gEmb, 256, 0, stream>>>(rp1, pk1, order0, embA, embB, embS, 1);
  k_num_step<<<(NN + 255) / 256, 256, 0, stream>>>(rp1, pk1, order0, order0, num1, numS, 1);
  // stage 2: cur=embB -> next=embA, S +=
  k_emb_step<<<gEmb, 256, 0, stream>>>(rp2, pk2, order1, embB, embA, embS, 2);
  k_num_step<<<(NN + 255) / 256, 256, 0, stream>>>(rp2, pk2, order1, num1, num2, numS, 2);
  // stage 3: cur=embA, S += only
  k_emb_step<<<gEmb, 256, 0, stream>>>(rp3, pk3, order2, embA, (float*)nullptr, embS, 3);
  k_num_step<<<(NN + 255) / 256, 256, 0, stream>>>(rp3, pk3, order2, num2, (float*)nullptr,
                                                   numS, 3);

  k_final<<<(NN + 255) / 256, 256, 0, stream>>>(embeds, embS, numS, 0u, 7u, out, hist);
  k_cutoff<<<1, 1024, 0, stream>>>(hist, cnt2 + 1);
  k_collect<<<(NN + 255) / 256, 256, 0, stream>>>(out, cnt2 + 1, buf, cnt2);
  k_sort<<<1, 1024, 0, stream>>>(buf, cnt2, out + NN);
}

// Round 3
// 565.830 us; speedup vs baseline: 2.1235x; 1.2185x over previous
//
#include <hip/hip_runtime.h>
#include <stdint.h>
#include <stddef.h>

#define NN 100000
#define NE 1600000
#define DD 32
#define NCAND 1024
#define HSIZE 65536
#define SORTN 4096
#define SCAN_B 1024
#define NB ((NN + SCAN_B - 1) / SCAN_B)   // 98 blocks per scan array
#define NTB 128                            // k_build2 block size
#define KMAX 64                            // max in-LDS degree (Poisson(16) max ~45)

// capacity for per-stage packed lists (mean + huge margin)
#define CAP1 832000
#define CAP2 432000
#define CAP3 240000

// ---------------- JAX threefry2x32 (20 rounds) ----------------
__host__ __device__ inline void tf2x32(uint32_t k0, uint32_t k1, uint32_t x0, uint32_t x1,
                                       uint32_t& o0, uint32_t& o1) {
  uint32_t ks2 = k0 ^ k1 ^ 0x1BD11BDAu;
  uint32_t v0 = x0 + k0, v1 = x1 + k1;
#define TFR(r) { v0 += v1; v1 = (v1 << (r)) | (v1 >> (32 - (r))); v1 ^= v0; }
  TFR(13) TFR(15) TFR(26) TFR(6)   v0 += k1;  v1 += ks2 + 1u;
  TFR(17) TFR(29) TFR(16) TFR(24)  v0 += ks2; v1 += k0 + 2u;
  TFR(13) TFR(15) TFR(26) TFR(6)   v0 += k0;  v1 += k1 + 3u;
  TFR(17) TFR(29) TFR(16) TFR(24)  v0 += k1;  v1 += ks2 + 4u;
  TFR(13) TFR(15) TFR(26) TFR(6)   v0 += ks2; v1 += k0 + 5u;
#undef TFR
  o0 = v0; o1 = v1;
}

__device__ __forceinline__ uint32_t jax_bits32(uint32_t k0, uint32_t k1, uint32_t i) {
  uint32_t o0, o1;
  tf2x32(k0, k1, 0u, i, o0, o1);
  return o0 ^ o1;
}

__device__ __forceinline__ float bits_to_uniform(uint32_t b) {
  return __fsub_rn(__uint_as_float((b >> 9) | 0x3f800000u), 1.0f);
}

// numpy-pairwise sum of 32 floats
__device__ __forceinline__ float pairwise32(const float* x) {
  float r[8];
#pragma unroll
  for (int j = 0; j < 8; ++j) r[j] = x[j];
#pragma unroll
  for (int b = 8; b < 32; b += 8)
#pragma unroll
    for (int j = 0; j < 8; ++j) r[j] = __fadd_rn(r[j], x[b + j]);
  float a01 = __fadd_rn(r[0], r[1]), a23 = __fadd_rn(r[2], r[3]);
  float a45 = __fadd_rn(r[4], r[5]), a67 = __fadd_rn(r[6], r[7]);
  return __fadd_rn(__fadd_rn(a01, a23), __fadd_rn(a45, a67));
}

// ---------------- kernels ----------------

// levels + packed per-row per-stage degree counts (one u64 atomic, 16-bit fields)
__global__ void k_level_count(const int* __restrict__ rows,
                              uint32_t k00, uint32_t k01, uint32_t k10, uint32_t k11,
                              uint32_t k20, uint32_t k21,
                              uint8_t* __restrict__ level,
                              unsigned long long* __restrict__ pcnt) {
  int e = blockIdx.x * blockDim.x + threadIdx.x;
  if (e >= NE) return;
  float u0 = bits_to_uniform(jax_bits32(k00, k01, (uint32_t)e));
  float u1 = bits_to_uniform(jax_bits32(k10, k11, (uint32_t)e));
  float u2 = bits_to_uniform(jax_bits32(k20, k21, (uint32_t)e));
  float kp0 = floorf(__fadd_rn(u0, 0.5f));
  float kp1 = floorf(__fadd_rn(u1, 0.25f));
  float kp2 = floorf(__fadd_rn(u2, 0.125f));
  int lv = 0;
  if (kp0 != 0.0f) { lv = 1; if (kp1 != 0.0f) { lv = 2; if (kp2 != 0.0f) lv = 3; } }
  level[e] = (uint8_t)lv;
  unsigned long long add = 1ull;
  if (lv >= 1) add |= 1ull << 16;
  if (lv >= 2) add |= 1ull << 32;
  if (lv >= 3) add |= 1ull << 48;
  atomicAdd(&pcnt[rows[e]], add);
}

// multi-array exclusive scan over packed 16-bit fields: grid (NB, 4)
__global__ void k_scan1(const unsigned long long* __restrict__ pcnt, int* __restrict__ rpAll,
                        int* __restrict__ bsumAll) {
  __shared__ int s[SCAN_B];
  int a = blockIdx.y;
  int* rp = rpAll + (size_t)a * (NN + 1);
  int gid = blockIdx.x * SCAN_B + threadIdx.x;
  int v = (gid < NN) ? (int)((pcnt[gid] >> (16 * a)) & 0xFFFFull) : 0;
  s[threadIdx.x] = v;
  __syncthreads();
  for (int off = 1; off < SCAN_B; off <<= 1) {
    int t = (threadIdx.x >= off) ? s[threadIdx.x - off] : 0;
    __syncthreads();
    s[threadIdx.x] += t;
    __syncthreads();
  }
  if (gid < NN) rp[gid] = s[threadIdx.x] - v;  // exclusive
  if (threadIdx.x == SCAN_B - 1) bsumAll[a * 128 + blockIdx.x] = s[threadIdx.x];
}

__global__ void k_scan2(int* __restrict__ bsumAll) {
  __shared__ int s[128];
  int* bsum = bsumAll + blockIdx.x * 128;
  int t = threadIdx.x;
  int v = (t < NB) ? bsum[t] : 0;
  s[t] = v;
  __syncthreads();
  for (int off = 1; off < 128; off <<= 1) {
    int x = (t >= off) ? s[t - off] : 0;
    __syncthreads();
    s[t] += x;
    __syncthreads();
  }
  if (t < NB) bsum[t] = s[t] - v;  // exclusive
}

__global__ void k_scan3(int* __restrict__ rpAll, const int* __restrict__ bsumAll,
                        const unsigned long long* __restrict__ pcnt) {
  int a = blockIdx.y;
  int* rp = rpAll + (size_t)a * (NN + 1);
  int gid = blockIdx.x * SCAN_B + threadIdx.x;
  if (gid < NN) {
    int v = rp[gid] + bsumAll[a * 128 + blockIdx.x];
    rp[gid] = v;
    if (gid == NN - 1) rp[NN] = v + (int)((pcnt[gid] >> (16 * a)) & 0xFFFFull);
  }
}

// edge-parallel: coalesced source reads, scattered 16B payload write into row segment
__global__ void k_scatter(const int* __restrict__ rows, const int* __restrict__ cols,
                          const float* __restrict__ adj, const uint8_t* __restrict__ level,
                          const int* __restrict__ rp0, int* __restrict__ cursor,
                          int4* __restrict__ pkRaw) {
  int e = blockIdx.x * blockDim.x + threadIdx.x;
  if (e >= NE) return;
  int c = cols[e];
  int ab = __float_as_int(adj[e]);
  int lv = (int)level[e];
  int r = rows[e];
  int pos = rp0[r] + atomicAdd(&cursor[r], 1);
  pkRaw[pos] = make_int4(c, ab, lv, e);
}

// per-row: LDS insertion sort of packed keys (eid<<6)|i, emit packed stage lists + orders
__global__ __launch_bounds__(NTB) void k_build2(
    const int* __restrict__ rpAll, int4* __restrict__ pkRaw,
    int2* __restrict__ pk0, int2* __restrict__ pk1,
    int2* __restrict__ pk2, int2* __restrict__ pk3,
    float* __restrict__ order0, float* __restrict__ order1, float* __restrict__ order2) {
  __shared__ uint32_t K[KMAX * NTB];  // transposed: K[i*NTB + t], bank = t%32 (2-way, free)
  int t = threadIdx.x;
  int r = blockIdx.x * NTB + t;
  if (r >= NN) return;  // no __syncthreads below; LDS column is thread-private
  const int* rp0 = rpAll;
  const int* rp1 = rpAll + (NN + 1);
  const int* rp2 = rpAll + 2 * (NN + 1);
  const int* rp3 = rpAll + 3 * (NN + 1);
  int s = rp0[r], en = rp0[r + 1];
  int d = en - s;
  int p0 = s, p1 = rp1[r], p2 = rp2[r], p3 = rp3[r];
  float o0 = 0.0f, o1 = 0.0f, o2 = 0.0f;
  if (d <= KMAX) {
    for (int i = 0; i < d; ++i) {
      int4 p = pkRaw[s + i];
      K[i * NTB + t] = ((uint32_t)p.w << 6) | (uint32_t)i;
    }
    for (int i = 1; i < d; ++i) {
      uint32_t key = K[i * NTB + t];
      int j = i - 1;
      while (j >= 0) {
        uint32_t kj = K[j * NTB + t];
        if (kj <= key) break;
        K[(j + 1) * NTB + t] = kj;
        --j;
      }
      K[(j + 1) * NTB + t] = key;
    }
    for (int i = 0; i < d; ++i) {
      int idx = (int)(K[i * NTB + t] & 63u);
      int4 p = pkRaw[s + idx];  // L1-hot re-read
      float a = __int_as_float(p.y);
      int lv = p.z;
      int2 pk = make_int2(p.x, p.y);
      o0 = __fadd_rn(o0, a);
      pk0[p0++] = pk;
      if (lv >= 1) {
        o1 = __fadd_rn(o1, a);
        pk1[p1++] = pk;
        if (lv >= 2) {
          o2 = __fadd_rn(o2, a);
          pk2[p2++] = pk;
          if (lv >= 3) pk3[p3++] = pk;
        }
      }
    }
  } else {
    // effectively-never fallback: global in-place insertion sort by eid
    for (int i = s + 1; i < en; ++i) {
      int4 key = pkRaw[i];
      int j = i - 1;
      while (j >= s && pkRaw[j].w > key.w) { pkRaw[j + 1] = pkRaw[j]; --j; }
      pkRaw[j + 1] = key;
    }
    for (int i = s; i < en; ++i) {
      int4 p = pkRaw[i];
      float a = __int_as_float(p.y);
      int lv = p.z;
      int2 pk = make_int2(p.x, p.y);
      o0 = __fadd_rn(o0, a);
      pk0[p0++] = pk;
      if (lv >= 1) {
        o1 = __fadd_rn(o1, a);
        pk1[p1++] = pk;
        if (lv >= 2) {
          o2 = __fadd_rn(o2, a);
          pk2[p2++] = pk;
          if (lv >= 3) pk3[p3++] = pk;
        }
      }
    }
  }
  order0[r] = o0; order1[r] = o1; order2[r] = o2;
}

// fst_emb = spmm(adj, embeds) - embeds  (write E0 only)
__global__ void k_emb0(const int* __restrict__ rp, const int2* __restrict__ pk,
                       const float* __restrict__ embeds, float* __restrict__ e0) {
  int tid = blockIdx.x * blockDim.x + threadIdx.x;
  int r = tid >> 5, d = tid & 31;
  if (r >= NN) return;
  int s = rp[r], t = rp[r + 1];
  float acc = 0.0f;
  for (int base = s; base < t; base += 32) {
    int idx = base + d;
    int2 p = (idx < t) ? pk[idx] : make_int2(0, 0);
    int m = t - base; if (m > 32) m = 32;
    for (int j = 0; j < m; ++j) {
      int c = __shfl(p.x, j, 32);
      int ab = __shfl(p.y, j, 32);
      float x = embeds[(size_t)c * DD + d];
      acc = __fadd_rn(acc, __fmul_rn(__int_as_float(ab), x));
    }
  }
  e0[(size_t)r * DD + d] = __fsub_rn(acc, embeds[(size_t)r * DD + d]);
}

// emb_next = spmm(stage vals, emb_cur) - emb_cur - order*emb_cur
// mode: 1 = S = ec + o (init), write next; 2 = S += o, write next; 3 = S += o only
__global__ void k_emb_step(const int* __restrict__ rp, const int2* __restrict__ pk,
                           const float* __restrict__ ord, const float* __restrict__ ecur,
                           float* __restrict__ enext, float* __restrict__ esum, int mode) {
  int tid = blockIdx.x * blockDim.x + threadIdx.x;
  int r = tid >> 5, d = tid & 31;
  if (r >= NN) return;
  int s = rp[r], t = rp[r + 1];
  float acc = 0.0f;
  for (int base = s; base < t; base += 32) {
    int idx = base + d;
    int2 p = (idx < t) ? pk[idx] : make_int2(0, 0);
    int m = t - base; if (m > 32) m = 32;
    for (int j = 0; j < m; ++j) {
      int c = __shfl(p.x, j, 32);
      int ab = __shfl(p.y, j, 32);
      float x = ecur[(size_t)c * DD + d];
      acc = __fadd_rn(acc, __fmul_rn(__int_as_float(ab), x));
    }
  }
  size_t idx = (size_t)r * DD + d;
  float ec = ecur[idx];
  float o = __fsub_rn(__fsub_rn(acc, ec), __fmul_rn(ord[r], ec));
  if (mode != 3) enext[idx] = o;
  if (mode == 1) esum[idx] = __fadd_rn(ec, o);
  else esum[idx] = __fadd_rn(esum[idx], o);
}

// num_next = spmm(stage vals, num_cur) - num_cur - order
__global__ void k_num_step(const int* __restrict__ rp, const int2* __restrict__ pk,
                           const float* __restrict__ ord, const float* __restrict__ ncur,
                           float* __restrict__ nnext, float* __restrict__ nsum, int mode) {
  int r = blockIdx.x * blockDim.x + threadIdx.x;
  if (r >= NN) return;
  int s = rp[r], t = rp[r + 1];
  float acc = 0.0f;
  for (int k = s; k < t; ++k) {
    int2 p = pk[k];
    acc = __fadd_rn(acc, __fmul_rn(__int_as_float(p.y), ncur[p.x]));
  }
  float nc = ncur[r];
  float o = __fsub_rn(__fsub_rn(acc, nc), ord[r]);
  if (mode != 3) nnext[r] = o;
  if (mode == 1) nsum[r] = __fadd_rn(nc, o);
  else nsum[r] = __fadd_rn(nsum[r], o);
}

__global__ void k_final(const float* __restrict__ embeds, const float* __restrict__ emb_sum,
                        const float* __restrict__ num_sum, uint32_t gk0, uint32_t gk1,
                        float* __restrict__ out_scores, int* __restrict__ hist) {
  int r = blockIdx.x * blockDim.x + threadIdx.x;
  if (r >= NN) return;
  float denom = __fadd_rn(num_sum[r], 1e-8f);
  float sub[DD], em[DD], pr[DD];
  const float4* ps = (const float4*)(emb_sum + (size_t)r * DD);
  const float4* pe = (const float4*)(embeds + (size_t)r * DD);
#pragma unroll
  for (int j = 0; j < 8; ++j) {
    float4 a = ps[j], b = pe[j];
    sub[4 * j + 0] = __fdiv_rn(a.x, denom); sub[4 * j + 1] = __fdiv_rn(a.y, denom);
    sub[4 * j + 2] = __fdiv_rn(a.z, denom); sub[4 * j + 3] = __fdiv_rn(a.w, denom);
    em[4 * j + 0] = b.x; em[4 * j + 1] = b.y; em[4 * j + 2] = b.z; em[4 * j + 3] = b.w;
  }
#pragma unroll
  for (int d = 0; d < DD; ++d) pr[d] = __fmul_rn(sub[d], sub[d]);
  float n1 = fmaxf(__fsqrt_rn(pairwise32(pr)), 1e-12f);
#pragma unroll
  for (int d = 0; d < DD; ++d) pr[d] = __fmul_rn(em[d], em[d]);
  float n2 = fmaxf(__fsqrt_rn(pairwise32(pr)), 1e-12f);
#pragma unroll
  for (int d = 0; d < DD; ++d)
    pr[d] = __fmul_rn(__fdiv_rn(sub[d], n1), __fdiv_rn(em[d], n2));
  float dot = pairwise32(pr);
  float u = bits_to_uniform(jax_bits32(gk0, gk1, (uint32_t)r));
  float l1 = (float)log((double)u);
  float w = -l1;
  float l2 = (float)log((double)w);
  float g = -l2;
  float score = __fadd_rn(dot, g);
  out_scores[r] = score;
  uint32_t kb = __float_as_uint(score);
  kb = (kb & 0x80000000u) ? ~kb : (kb | 0x80000000u);
  atomicAdd(&hist[kb >> 16], 1);
}

__global__ void k_cutoff(const int* __restrict__ hist, int* __restrict__ cutoff) {
  __shared__ int psum[1024];
  int t = threadIdx.x;
  int base = HSIZE - (t + 1) * 64;
  int own = 0;
  for (int i = 0; i < 64; ++i) own += hist[base + i];
  psum[t] = own;
  __syncthreads();
  for (int off = 1; off < 1024; off <<= 1) {
    int v = (t >= off) ? psum[t - off] : 0;
    __syncthreads();
    psum[t] += v;
    __syncthreads();
  }
  int incl = psum[t];
  int prev = incl - own;
  if (incl >= NCAND && prev < NCAND) {
    int c = prev;
    int b = HSIZE - t * 64 - 1;
    while (b >= base) {
      c += hist[b];
      if (c >= NCAND) break;
      --b;
    }
    *cutoff = b;
  }
}

__global__ void k_collect(const float* __restrict__ scores, const int* __restrict__ cutoff,
                          unsigned long long* __restrict__ buf, int* __restrict__ cnt2) {
  int r = blockIdx.x * blockDim.x + threadIdx.x;
  if (r >= NN) return;
  uint32_t kb = __float_as_uint(scores[r]);
  kb = (kb & 0x80000000u) ? ~kb : (kb | 0x80000000u);
  if ((int)(kb >> 16) >= *cutoff) {
    int p = atomicAdd(cnt2, 1);
    if (p < SORTN)
      buf[p] = ((unsigned long long)kb << 32) | (uint32_t)(~(uint32_t)r);
  }
}

__global__ __launch_bounds__(1024) void k_sort(const unsigned long long* __restrict__ buf,
                                               const int* __restrict__ cnt2,
                                               float* __restrict__ out_cand) {
  __shared__ unsigned long long s[SORTN];
  int m = *cnt2;
  if (m > SORTN) m = SORTN;
  for (int i = threadIdx.x; i < SORTN; i += 1024) s[i] = (i < m) ? buf[i] : 0ull;
  __syncthreads();
  for (int k = 2; k <= SORTN; k <<= 1) {
    for (int j = k >> 1; j > 0; j >>= 1) {
      for (int i = threadIdx.x; i < SORTN; i += 1024) {
        int ixj = i ^ j;
        if (ixj > i) {
          unsigned long long a = s[i], b = s[ixj];
          bool desc = ((i & k) == 0);
          if (desc ? (a < b) : (a > b)) { s[i] = b; s[ixj] = a; }
        }
      }
      __syncthreads();
    }
  }
  for (int i = threadIdx.x; i < NCAND; i += 1024) {
    uint32_t idx = ~((uint32_t)(s[i] & 0xffffffffull));
    out_cand[i] = (float)idx;
  }
}

// ---------------- host ----------------
extern "C" void kernel_launch(void* const* d_in, const int* in_sizes, int n_in,
                              void* d_out, int out_size, void* d_ws, size_t ws_size,
                              hipStream_t stream) {
  const int* rows = (const int*)d_in[0];
  const int* cols = rows + NE;
  const float* adj = (const float*)d_in[1];
  const float* embeds = (const float*)d_in[2];
  float* out = (float*)d_out;

  char* p = (char*)d_ws;
  auto alloc = [&](size_t bytes) {
    char* q = p;
    p += (bytes + 255) & ~(size_t)255;
    return q;
  };
  // single contiguous zero region: pcnt(u64 x NN) | cursor(NN) | hist | cnt2
  size_t zero_bytes = (size_t)NN * 8 + (size_t)NN * 4 + (size_t)HSIZE * 4 + 256;
  char* zero_base = (char*)alloc(zero_bytes);
  unsigned long long* pcnt = (unsigned long long*)zero_base;
  int* cursor = (int*)(pcnt + NN);
  int* hist = cursor + NN;
  int* cnt2 = hist + HSIZE;  // [0]=collect count, [1]=cutoff bin

  int* rpAll = (int*)alloc((size_t)4 * (NN + 1) * 4);
  int* bsumAll = (int*)alloc(4 * 128 * 4);
  uint8_t* level = (uint8_t*)alloc(NE);
  // pkRaw (25.6 MB) aliases embA+embB: dead before k_emb0 writes embA
  char* unionAB = (char*)alloc((size_t)NE * 16);
  int4* pkRaw = (int4*)unionAB;
  float* embA = (float*)unionAB;                           // 12.8 MB
  float* embB = (float*)(unionAB + (size_t)NN * DD * 4);   // 12.8 MB
  int2* pk0 = (int2*)alloc((size_t)NE * 8);
  int2* pk1 = (int2*)alloc((size_t)CAP1 * 8);
  int2* pk2 = (int2*)alloc((size_t)CAP2 * 8);
  int2* pk3 = (int2*)alloc((size_t)CAP3 * 8);
  float* order0 = (float*)alloc(NN * 4);
  float* order1 = (float*)alloc(NN * 4);
  float* order2 = (float*)alloc(NN * 4);
  float* embS = (float*)alloc((size_t)NN * DD * 4);
  float* num1 = (float*)alloc(NN * 4);
  float* num2 = (float*)alloc(NN * 4);
  float* numS = (float*)alloc(NN * 4);
  unsigned long long* buf = (unsigned long long*)alloc(SORTN * 8);

  uint32_t dk[3][2];
  for (int i = 0; i < 3; ++i) tf2x32(0u, 42u, 0u, (uint32_t)i, dk[i][0], dk[i][1]);

  hipMemsetAsync(zero_base, 0, zero_bytes, stream);

  k_level_count<<<(NE + 255) / 256, 256, 0, stream>>>(
      rows, dk[0][0], dk[0][1], dk[1][0], dk[1][1], dk[2][0], dk[2][1], level, pcnt);

  dim3 sg(NB, 4);
  k_scan1<<<sg, SCAN_B, 0, stream>>>(pcnt, rpAll, bsumAll);
  k_scan2<<<4, 128, 0, stream>>>(bsumAll);
  k_scan3<<<sg, SCAN_B, 0, stream>>>(rpAll, bsumAll, pcnt);

  k_scatter<<<(NE + 255) / 256, 256, 0, stream>>>(rows, cols, adj, level, rpAll, cursor,
                                                  pkRaw);
  k_build2<<<(NN + NTB - 1) / NTB, NTB, 0, stream>>>(rpAll, pkRaw, pk0, pk1, pk2, pk3,
                                                     order0, order1, order2);

  const int* rp0 = rpAll;
  const int* rp1 = rpAll + (NN + 1);
  const int* rp2 = rpAll + 2 * (NN + 1);
  const int* rp3 = rpAll + 3 * (NN + 1);

  int gEmb = (NN * 32 + 255) / 256;
  k_emb0<<<gEmb, 256, 0, stream>>>(rp0, pk0, embeds, embA);

  // stage 1: cur=embA -> next=embB, S init
  k_emb_step<<<gEmb, 256, 0, stream>>>(rp1, pk1, order0, embA, embB, embS, 1);
  k_num_step<<<(NN + 255) / 256, 256, 0, stream>>>(rp1, pk1, order0, order0, num1, numS, 1);
  // stage 2: cur=embB -> next=embA, S +=
  k_emb_step<<<gEmb, 256, 0, stream>>>(rp2, pk2, order1, embB, embA, embS, 2);
  k_num_step<<<(NN + 255) / 256, 256, 0, stream>>>(rp2, pk2, order1, num1, num2, numS, 2);
  // stage 3: cur=embA, S += only
  k_emb_step<<<gEmb, 256, 0, stream>>>(rp3, pk3, order2, embA, (float*)nullptr, embS, 3);
  k_num_step<<<(NN + 255) / 256, 256, 0, stream>>>(rp3, pk3, order2, num2, (float*)nullptr,
                                                   numS, 3);

  k_final<<<(NN + 255) / 256, 256, 0, stream>>>(embeds, embS, numS, 0u, 7u, out, hist);
  k_cutoff<<<1, 1024, 0, stream>>>(hist, cnt2 + 1);
  k_collect<<<(NN + 255) / 256, 256, 0, stream>>>(out, cnt2 + 1, buf, cnt2);
  k_sort<<<1, 1024, 0, stream>>>(buf, cnt2, out + NN);
}

// Round 4
// 524.179 us; speedup vs baseline: 2.2922x; 1.0795x over previous
//
#include <hip/hip_runtime.h>
#include <stdint.h>
#include <stddef.h>

#define NN 100000
#define NE 1600000
#define DD 32
#define NCAND 1024
#define HSIZE 65536
#define SORTN 4096
#define SCAN_B 1024
#define NB ((NN + SCAN_B - 1) / SCAN_B)   // 98 blocks per scan array
#define NTB 128                            // k_build2 block size
#define KMAX 64                            // max in-LDS degree (Poisson(16) max ~45)

// capacity for per-stage packed lists (mean + huge margin)
#define CAP1 832000
#define CAP2 432000
#define CAP3 240000

// ---------------- JAX threefry2x32 (20 rounds) ----------------
__host__ __device__ inline void tf2x32(uint32_t k0, uint32_t k1, uint32_t x0, uint32_t x1,
                                       uint32_t& o0, uint32_t& o1) {
  uint32_t ks2 = k0 ^ k1 ^ 0x1BD11BDAu;
  uint32_t v0 = x0 + k0, v1 = x1 + k1;
#define TFR(r) { v0 += v1; v1 = (v1 << (r)) | (v1 >> (32 - (r))); v1 ^= v0; }
  TFR(13) TFR(15) TFR(26) TFR(6)   v0 += k1;  v1 += ks2 + 1u;
  TFR(17) TFR(29) TFR(16) TFR(24)  v0 += ks2; v1 += k0 + 2u;
  TFR(13) TFR(15) TFR(26) TFR(6)   v0 += k0;  v1 += k1 + 3u;
  TFR(17) TFR(29) TFR(16) TFR(24)  v0 += k1;  v1 += ks2 + 4u;
  TFR(13) TFR(15) TFR(26) TFR(6)   v0 += ks2; v1 += k0 + 5u;
#undef TFR
  o0 = v0; o1 = v1;
}

__device__ __forceinline__ uint32_t jax_bits32(uint32_t k0, uint32_t k1, uint32_t i) {
  uint32_t o0, o1;
  tf2x32(k0, k1, 0u, i, o0, o1);
  return o0 ^ o1;
}

__device__ __forceinline__ float bits_to_uniform(uint32_t b) {
  return __fsub_rn(__uint_as_float((b >> 9) | 0x3f800000u), 1.0f);
}

// numpy-pairwise sum of 32 floats
__device__ __forceinline__ float pairwise32(const float* x) {
  float r[8];
#pragma unroll
  for (int j = 0; j < 8; ++j) r[j] = x[j];
#pragma unroll
  for (int b = 8; b < 32; b += 8)
#pragma unroll
    for (int j = 0; j < 8; ++j) r[j] = __fadd_rn(r[j], x[b + j]);
  float a01 = __fadd_rn(r[0], r[1]), a23 = __fadd_rn(r[2], r[3]);
  float a45 = __fadd_rn(r[4], r[5]), a67 = __fadd_rn(r[6], r[7]);
  return __fadd_rn(__fadd_rn(a01, a23), __fadd_rn(a45, a67));
}

// ---------------- kernels ----------------

// levels + packed per-row per-stage counts (one u64 atomic, 16-bit fields).
// The atomic's returned old value's low field = per-row sequence number -> seq16[e].
__global__ void k_level_count(const int* __restrict__ rows,
                              uint32_t k00, uint32_t k01, uint32_t k10, uint32_t k11,
                              uint32_t k20, uint32_t k21,
                              uint8_t* __restrict__ level,
                              unsigned long long* __restrict__ pcnt,
                              uint16_t* __restrict__ seq16) {
  int e = blockIdx.x * blockDim.x + threadIdx.x;
  if (e >= NE) return;
  float u0 = bits_to_uniform(jax_bits32(k00, k01, (uint32_t)e));
  float u1 = bits_to_uniform(jax_bits32(k10, k11, (uint32_t)e));
  float u2 = bits_to_uniform(jax_bits32(k20, k21, (uint32_t)e));
  float kp0 = floorf(__fadd_rn(u0, 0.5f));
  float kp1 = floorf(__fadd_rn(u1, 0.25f));
  float kp2 = floorf(__fadd_rn(u2, 0.125f));
  int lv = 0;
  if (kp0 != 0.0f) { lv = 1; if (kp1 != 0.0f) { lv = 2; if (kp2 != 0.0f) lv = 3; } }
  level[e] = (uint8_t)lv;
  unsigned long long add = 1ull;
  if (lv >= 1) add |= 1ull << 16;
  if (lv >= 2) add |= 1ull << 32;
  if (lv >= 3) add |= 1ull << 48;
  unsigned long long old = atomicAdd(&pcnt[rows[e]], add);
  seq16[e] = (uint16_t)(old & 0xFFFFull);  // field 0 = prior count of this row
}

// multi-array exclusive scan over packed 16-bit fields: grid (NB, 4)
__global__ void k_scan1(const unsigned long long* __restrict__ pcnt, int* __restrict__ rpAll,
                        int* __restrict__ bsumAll) {
  __shared__ int s[SCAN_B];
  int a = blockIdx.y;
  int* rp = rpAll + (size_t)a * (NN + 1);
  int gid = blockIdx.x * SCAN_B + threadIdx.x;
  int v = (gid < NN) ? (int)((pcnt[gid] >> (16 * a)) & 0xFFFFull) : 0;
  s[threadIdx.x] = v;
  __syncthreads();
  for (int off = 1; off < SCAN_B; off <<= 1) {
    int t = (threadIdx.x >= off) ? s[threadIdx.x - off] : 0;
    __syncthreads();
    s[threadIdx.x] += t;
    __syncthreads();
  }
  if (gid < NN) rp[gid] = s[threadIdx.x] - v;  // exclusive
  if (threadIdx.x == SCAN_B - 1) bsumAll[a * 128 + blockIdx.x] = s[threadIdx.x];
}

__global__ void k_scan2(int* __restrict__ bsumAll) {
  __shared__ int s[128];
  int* bsum = bsumAll + blockIdx.x * 128;
  int t = threadIdx.x;
  int v = (t < NB) ? bsum[t] : 0;
  s[t] = v;
  __syncthreads();
  for (int off = 1; off < 128; off <<= 1) {
    int x = (t >= off) ? s[t - off] : 0;
    __syncthreads();
    s[t] += x;
    __syncthreads();
  }
  if (t < NB) bsum[t] = s[t] - v;  // exclusive
}

__global__ void k_scan3(int* __restrict__ rpAll, const int* __restrict__ bsumAll,
                        const unsigned long long* __restrict__ pcnt) {
  int a = blockIdx.y;
  int* rp = rpAll + (size_t)a * (NN + 1);
  int gid = blockIdx.x * SCAN_B + threadIdx.x;
  if (gid < NN) {
    int v = rp[gid] + bsumAll[a * 128 + blockIdx.x];
    rp[gid] = v;
    if (gid == NN - 1) rp[NN] = v + (int)((pcnt[gid] >> (16 * a)) & 0xFFFFull);
  }
}

// edge-parallel: coalesced source reads, one scattered 16B write, no atomics
__global__ void k_scatter(const int* __restrict__ rows, const int* __restrict__ cols,
                          const float* __restrict__ adj, const uint8_t* __restrict__ level,
                          const uint16_t* __restrict__ seq16, const int* __restrict__ rp0,
                          int4* __restrict__ pkRaw) {
  int e = blockIdx.x * blockDim.x + threadIdx.x;
  if (e >= NE) return;
  int c = cols[e];
  int ab = __float_as_int(adj[e]);
  int lv = (int)level[e];
  int r = rows[e];
  int pos = rp0[r] + (int)seq16[e];
  pkRaw[pos] = make_int4(c, ab, lv, e);
}

// per-row: LDS insertion sort of packed keys (eid<<6)|i, emit packed stage lists + orders
__global__ __launch_bounds__(NTB) void k_build2(
    const int* __restrict__ rpAll, int4* __restrict__ pkRaw,
    int2* __restrict__ pk0, int2* __restrict__ pk1,
    int2* __restrict__ pk2, int2* __restrict__ pk3,
    float* __restrict__ order0, float* __restrict__ order1, float* __restrict__ order2) {
  __shared__ uint32_t K[KMAX * NTB];  // transposed: K[i*NTB + t], bank = t%32 (2-way, free)
  int t = threadIdx.x;
  int r = blockIdx.x * NTB + t;
  if (r >= NN) return;  // no __syncthreads below; LDS column is thread-private
  const int* rp0 = rpAll;
  const int* rp1 = rpAll + (NN + 1);
  const int* rp2 = rpAll + 2 * (NN + 1);
  const int* rp3 = rpAll + 3 * (NN + 1);
  int s = rp0[r], en = rp0[r + 1];
  int d = en - s;
  int p0 = s, p1 = rp1[r], p2 = rp2[r], p3 = rp3[r];
  float o0 = 0.0f, o1 = 0.0f, o2 = 0.0f;
  if (d <= KMAX) {
    for (int i = 0; i < d; ++i) {
      int4 p = pkRaw[s + i];
      K[i * NTB + t] = ((uint32_t)p.w << 6) | (uint32_t)i;
    }
    for (int i = 1; i < d; ++i) {
      uint32_t key = K[i * NTB + t];
      int j = i - 1;
      while (j >= 0) {
        uint32_t kj = K[j * NTB + t];
        if (kj <= key) break;
        K[(j + 1) * NTB + t] = kj;
        --j;
      }
      K[(j + 1) * NTB + t] = key;
    }
    for (int i = 0; i < d; ++i) {
      int idx = (int)(K[i * NTB + t] & 63u);
      int4 p = pkRaw[s + idx];  // L1-hot re-read
      float a = __int_as_float(p.y);
      int lv = p.z;
      int2 pk = make_int2(p.x, p.y);
      o0 = __fadd_rn(o0, a);
      pk0[p0++] = pk;
      if (lv >= 1) {
        o1 = __fadd_rn(o1, a);
        pk1[p1++] = pk;
        if (lv >= 2) {
          o2 = __fadd_rn(o2, a);
          pk2[p2++] = pk;
          if (lv >= 3) pk3[p3++] = pk;
        }
      }
    }
  } else {
    // effectively-never fallback: global in-place insertion sort by eid
    for (int i = s + 1; i < en; ++i) {
      int4 key = pkRaw[i];
      int j = i - 1;
      while (j >= s && pkRaw[j].w > key.w) { pkRaw[j + 1] = pkRaw[j]; --j; }
      pkRaw[j + 1] = key;
    }
    for (int i = s; i < en; ++i) {
      int4 p = pkRaw[i];
      float a = __int_as_float(p.y);
      int lv = p.z;
      int2 pk = make_int2(p.x, p.y);
      o0 = __fadd_rn(o0, a);
      pk0[p0++] = pk;
      if (lv >= 1) {
        o1 = __fadd_rn(o1, a);
        pk1[p1++] = pk;
        if (lv >= 2) {
          o2 = __fadd_rn(o2, a);
          pk2[p2++] = pk;
          if (lv >= 3) pk3[p3++] = pk;
        }
      }
    }
  }
  order0[r] = o0; order1[r] = o1; order2[r] = o2;
}

// fst_emb = spmm(adj, embeds) - embeds  (write E0 only)
__global__ void k_emb0(const int* __restrict__ rp, const int2* __restrict__ pk,
                       const float* __restrict__ embeds, float* __restrict__ e0) {
  int tid = blockIdx.x * blockDim.x + threadIdx.x;
  int r = tid >> 5, d = tid & 31;
  if (r >= NN) return;
  int s = rp[r], t = rp[r + 1];
  float acc = 0.0f;
  for (int base = s; base < t; base += 32) {
    int idx = base + d;
    int2 p = (idx < t) ? pk[idx] : make_int2(0, 0);
    int m = t - base; if (m > 32) m = 32;
    for (int j = 0; j < m; ++j) {
      int c = __shfl(p.x, j, 32);
      int ab = __shfl(p.y, j, 32);
      float x = embeds[(size_t)c * DD + d];
      acc = __fadd_rn(acc, __fmul_rn(__int_as_float(ab), x));
    }
  }
  e0[(size_t)r * DD + d] = __fsub_rn(acc, embeds[(size_t)r * DD + d]);
}

// emb_next = spmm(stage vals, emb_cur) - emb_cur - order*emb_cur
// mode: 1 = S = ec + o (init), write next; 2 = S += o, write next; 3 = S += o only
__global__ void k_emb_step(const int* __restrict__ rp, const int2* __restrict__ pk,
                           const float* __restrict__ ord, const float* __restrict__ ecur,
                           float* __restrict__ enext, float* __restrict__ esum, int mode) {
  int tid = blockIdx.x * blockDim.x + threadIdx.x;
  int r = tid >> 5, d = tid & 31;
  if (r >= NN) return;
  int s = rp[r], t = rp[r + 1];
  float acc = 0.0f;
  for (int base = s; base < t; base += 32) {
    int idx = base + d;
    int2 p = (idx < t) ? pk[idx] : make_int2(0, 0);
    int m = t - base; if (m > 32) m = 32;
    for (int j = 0; j < m; ++j) {
      int c = __shfl(p.x, j, 32);
      int ab = __shfl(p.y, j, 32);
      float x = ecur[(size_t)c * DD + d];
      acc = __fadd_rn(acc, __fmul_rn(__int_as_float(ab), x));
    }
  }
  size_t idx = (size_t)r * DD + d;
  float ec = ecur[idx];
  float o = __fsub_rn(__fsub_rn(acc, ec), __fmul_rn(ord[r], ec));
  if (mode != 3) enext[idx] = o;
  if (mode == 1) esum[idx] = __fadd_rn(ec, o);
  else esum[idx] = __fadd_rn(esum[idx], o);
}

// num_next = spmm(stage vals, num_cur) - num_cur - order
__global__ void k_num_step(const int* __restrict__ rp, const int2* __restrict__ pk,
                           const float* __restrict__ ord, const float* __restrict__ ncur,
                           float* __restrict__ nnext, float* __restrict__ nsum, int mode) {
  int r = blockIdx.x * blockDim.x + threadIdx.x;
  if (r >= NN) return;
  int s = rp[r], t = rp[r + 1];
  float acc = 0.0f;
  for (int k = s; k < t; ++k) {
    int2 p = pk[k];
    acc = __fadd_rn(acc, __fmul_rn(__int_as_float(p.y), ncur[p.x]));
  }
  float nc = ncur[r];
  float o = __fsub_rn(__fsub_rn(acc, nc), ord[r]);
  if (mode != 3) nnext[r] = o;
  if (mode == 1) nsum[r] = __fadd_rn(nc, o);
  else nsum[r] = __fadd_rn(nsum[r], o);
}

__global__ void k_final(const float* __restrict__ embeds, const float* __restrict__ emb_sum,
                        const float* __restrict__ num_sum, uint32_t gk0, uint32_t gk1,
                        float* __restrict__ out_scores, int* __restrict__ hist) {
  int r = blockIdx.x * blockDim.x + threadIdx.x;
  if (r >= NN) return;
  float denom = __fadd_rn(num_sum[r], 1e-8f);
  float sub[DD], em[DD], pr[DD];
  const float4* ps = (const float4*)(emb_sum + (size_t)r * DD);
  const float4* pe = (const float4*)(embeds + (size_t)r * DD);
#pragma unroll
  for (int j = 0; j < 8; ++j) {
    float4 a = ps[j], b = pe[j];
    sub[4 * j + 0] = __fdiv_rn(a.x, denom); sub[4 * j + 1] = __fdiv_rn(a.y, denom);
    sub[4 * j + 2] = __fdiv_rn(a.z, denom); sub[4 * j + 3] = __fdiv_rn(a.w, denom);
    em[4 * j + 0] = b.x; em[4 * j + 1] = b.y; em[4 * j + 2] = b.z; em[4 * j + 3] = b.w;
  }
#pragma unroll
  for (int d = 0; d < DD; ++d) pr[d] = __fmul_rn(sub[d], sub[d]);
  float n1 = fmaxf(__fsqrt_rn(pairwise32(pr)), 1e-12f);
#pragma unroll
  for (int d = 0; d < DD; ++d) pr[d] = __fmul_rn(em[d], em[d]);
  float n2 = fmaxf(__fsqrt_rn(pairwise32(pr)), 1e-12f);
#pragma unroll
  for (int d = 0; d < DD; ++d)
    pr[d] = __fmul_rn(__fdiv_rn(sub[d], n1), __fdiv_rn(em[d], n2));
  float dot = pairwise32(pr);
  float u = bits_to_uniform(jax_bits32(gk0, gk1, (uint32_t)r));
  float l1 = (float)log((double)u);
  float w = -l1;
  float l2 = (float)log((double)w);
  float g = -l2;
  float score = __fadd_rn(dot, g);
  out_scores[r] = score;
  uint32_t kb = __float_as_uint(score);
  kb = (kb & 0x80000000u) ? ~kb : (kb | 0x80000000u);
  atomicAdd(&hist[kb >> 16], 1);
}

__global__ void k_cutoff(const int* __restrict__ hist, int* __restrict__ cutoff) {
  __shared__ int psum[1024];
  int t = threadIdx.x;
  int base = HSIZE - (t + 1) * 64;
  int own = 0;
  for (int i = 0; i < 64; ++i) own += hist[base + i];
  psum[t] = own;
  __syncthreads();
  for (int off = 1; off < 1024; off <<= 1) {
    int v = (t >= off) ? psum[t - off] : 0;
    __syncthreads();
    psum[t] += v;
    __syncthreads();
  }
  int incl = psum[t];
  int prev = incl - own;
  if (incl >= NCAND && prev < NCAND) {
    int c = prev;
    int b = HSIZE - t * 64 - 1;
    while (b >= base) {
      c += hist[b];
      if (c >= NCAND) break;
      --b;
    }
    *cutoff = b;
  }
}

__global__ void k_collect(const float* __restrict__ scores, const int* __restrict__ cutoff,
                          unsigned long long* __restrict__ buf, int* __restrict__ cnt2) {
  int r = blockIdx.x * blockDim.x + threadIdx.x;
  if (r >= NN) return;
  uint32_t kb = __float_as_uint(scores[r]);
  kb = (kb & 0x80000000u) ? ~kb : (kb | 0x80000000u);
  if ((int)(kb >> 16) >= *cutoff) {
    int p = atomicAdd(cnt2, 1);
    if (p < SORTN)
      buf[p] = ((unsigned long long)kb << 32) | (uint32_t)(~(uint32_t)r);
  }
}

__global__ __launch_bounds__(1024) void k_sort(const unsigned long long* __restrict__ buf,
                                               const int* __restrict__ cnt2,
                                               float* __restrict__ out_cand) {
  __shared__ unsigned long long s[SORTN];
  int m = *cnt2;
  if (m > SORTN) m = SORTN;
  for (int i = threadIdx.x; i < SORTN; i += 1024) s[i] = (i < m) ? buf[i] : 0ull;
  __syncthreads();
  for (int k = 2; k <= SORTN; k <<= 1) {
    for (int j = k >> 1; j > 0; j >>= 1) {
      for (int i = threadIdx.x; i < SORTN; i += 1024) {
        int ixj = i ^ j;
        if (ixj > i) {
          unsigned long long a = s[i], b = s[ixj];
          bool desc = ((i & k) == 0);
          if (desc ? (a < b) : (a > b)) { s[i] = b; s[ixj] = a; }
        }
      }
      __syncthreads();
    }
  }
  for (int i = threadIdx.x; i < NCAND; i += 1024) {
    uint32_t idx = ~((uint32_t)(s[i] & 0xffffffffull));
    out_cand[i] = (float)idx;
  }
}

// ---------------- host ----------------
extern "C" void kernel_launch(void* const* d_in, const int* in_sizes, int n_in,
                              void* d_out, int out_size, void* d_ws, size_t ws_size,
                              hipStream_t stream) {
  const int* rows = (const int*)d_in[0];
  const int* cols = rows + NE;
  const float* adj = (const float*)d_in[1];
  const float* embeds = (const float*)d_in[2];
  float* out = (float*)d_out;

  char* p = (char*)d_ws;
  auto alloc = [&](size_t bytes) {
    char* q = p;
    p += (bytes + 255) & ~(size_t)255;
    return q;
  };
  // single contiguous zero region: pcnt(u64 x NN) | hist | cnt2
  size_t zero_bytes = (size_t)NN * 8 + (size_t)HSIZE * 4 + 256;
  char* zero_base = (char*)alloc(zero_bytes);
  unsigned long long* pcnt = (unsigned long long*)zero_base;
  int* hist = (int*)(pcnt + NN);
  int* cnt2 = hist + HSIZE;  // [0]=collect count, [1]=cutoff bin

  int* rpAll = (int*)alloc((size_t)4 * (NN + 1) * 4);
  int* bsumAll = (int*)alloc(4 * 128 * 4);
  uint8_t* level = (uint8_t*)alloc(NE);
  uint16_t* seq16 = (uint16_t*)alloc((size_t)NE * 2);
  // pkRaw (25.6 MB) aliases embA+embB: dead before k_emb0 writes embA
  char* unionAB = (char*)alloc((size_t)NE * 16);
  int4* pkRaw = (int4*)unionAB;
  float* embA = (float*)unionAB;                           // 12.8 MB
  float* embB = (float*)(unionAB + (size_t)NN * DD * 4);   // 12.8 MB
  int2* pk0 = (int2*)alloc((size_t)NE * 8);
  int2* pk1 = (int2*)alloc((size_t)CAP1 * 8);
  int2* pk2 = (int2*)alloc((size_t)CAP2 * 8);
  int2* pk3 = (int2*)alloc((size_t)CAP3 * 8);
  float* order0 = (float*)alloc(NN * 4);
  float* order1 = (float*)alloc(NN * 4);
  float* order2 = (float*)alloc(NN * 4);
  float* embS = (float*)alloc((size_t)NN * DD * 4);
  float* num1 = (float*)alloc(NN * 4);
  float* num2 = (float*)alloc(NN * 4);
  float* numS = (float*)alloc(NN * 4);
  unsigned long long* buf = (unsigned long long*)alloc(SORTN * 8);

  uint32_t dk[3][2];
  for (int i = 0; i < 3; ++i) tf2x32(0u, 42u, 0u, (uint32_t)i, dk[i][0], dk[i][1]);

  hipMemsetAsync(zero_base, 0, zero_bytes, stream);

  k_level_count<<<(NE + 255) / 256, 256, 0, stream>>>(
      rows, dk[0][0], dk[0][1], dk[1][0], dk[1][1], dk[2][0], dk[2][1], level, pcnt, seq16);

  dim3 sg(NB, 4);
  k_scan1<<<sg, SCAN_B, 0, stream>>>(pcnt, rpAll, bsumAll);
  k_scan2<<<4, 128, 0, stream>>>(bsumAll);
  k_scan3<<<sg, SCAN_B, 0, stream>>>(rpAll, bsumAll, pcnt);

  k_scatter<<<(NE + 255) / 256, 256, 0, stream>>>(rows, cols, adj, level, seq16, rpAll,
                                                  pkRaw);
  k_build2<<<(NN + NTB - 1) / NTB, NTB, 0, stream>>>(rpAll, pkRaw, pk0, pk1, pk2, pk3,
                                                     order0, order1, order2);

  const int* rp0 = rpAll;
  const int* rp1 = rpAll + (NN + 1);
  const int* rp2 = rpAll + 2 * (NN + 1);
  const int* rp3 = rpAll + 3 * (NN + 1);

  int gEmb = (NN * 32 + 255) / 256;
  k_emb0<<<gEmb, 256, 0, stream>>>(rp0, pk0, embeds, embA);

  // stage 1: cur=embA -> next=embB, S init
  k_emb_step<<<gEmb, 256, 0, stream>>>(rp1, pk1, order0, embA, embB, embS, 1);
  k_num_step<<<(NN + 255) / 256, 256, 0, stream>>>(rp1, pk1, order0, order0, num1, numS, 1);
  // stage 2: cur=embB -> next=embA, S +=
  k_emb_step<<<gEmb, 256, 0, stream>>>(rp2, pk2, order1, embB, embA, embS, 2);
  k_num_step<<<(NN + 255) / 256, 256, 0, stream>>>(rp2, pk2, order1, num1, num2, numS, 2);
  // stage 3: cur=embA, S += only
  k_emb_step<<<gEmb, 256, 0, stream>>>(rp3, pk3, order2, embA, (float*)nullptr, embS, 3);
  k_num_step<<<(NN + 255) / 256, 256, 0, stream>>>(rp3, pk3, order2, num2, (float*)nullptr,
                                                   numS, 3);

  k_final<<<(NN + 255) / 256, 256, 0, stream>>>(embeds, embS, numS, 0u, 7u, out, hist);
  k_cutoff<<<1, 1024, 0, stream>>>(hist, cnt2 + 1);
  k_collect<<<(NN + 255) / 256, 256, 0, stream>>>(out, cnt2 + 1, buf, cnt2);
  k_sort<<<1, 1024, 0, stream>>>(buf, cnt2, out + NN);
}